// Round 1
// baseline (9262.315 us; speedup 1.0000x reference)
//
#include <hip/hip_runtime.h>
#include <hip/hip_bf16.h>
#include <math.h>

#define B_SZ 8
#define L_SZ 2048
#define D_SZ 1024
#define H_SZ 16
#define DK_SZ 64
#define TOPK 7
#define M_SZ (B_SZ * L_SZ)   // 16384

// ---------------------------------------------------------------------------
// K1: Y = X @ W^T + bias   (X: [M,K] row-major, W: [N,K] row-major)
// 64x64 tile, BK=16, 256 threads, 4x4 microtile, fp32.
// ---------------------------------------------------------------------------
#define BM 64
#define BN 64
#define BK 16
#define LDP (BM + 4)   // padded LDS stride (floats); keeps float4 16B-aligned

__global__ __launch_bounds__(256)
void sgemm_bias_xt(const float* __restrict__ X, const float* __restrict__ W,
                   const float* __restrict__ bias, float* __restrict__ Y,
                   int M, int N, int K) {
    __shared__ __align__(16) float As[BK][LDP];
    __shared__ __align__(16) float Bs[BK][LDP];
    const int tid = threadIdx.x;
    const int tx = tid & 15;     // -> n
    const int ty = tid >> 4;     // -> m
    const size_t m0 = (size_t)blockIdx.y * BM;
    const size_t n0 = (size_t)blockIdx.x * BN;

    const int lr = tid >> 2;        // 0..63 : row within tile
    const int lk = (tid & 3) * 4;   // 0,4,8,12 : k within tile

    float acc[4][4];
#pragma unroll
    for (int i = 0; i < 4; ++i)
#pragma unroll
        for (int j = 0; j < 4; ++j) acc[i][j] = 0.f;

    for (int k0 = 0; k0 < K; k0 += BK) {
        float4 a4 = *(const float4*)(X + (m0 + lr) * K + k0 + lk);
        float4 b4 = *(const float4*)(W + (n0 + lr) * K + k0 + lk);
        As[lk + 0][lr] = a4.x; As[lk + 1][lr] = a4.y;
        As[lk + 2][lr] = a4.z; As[lk + 3][lr] = a4.w;
        Bs[lk + 0][lr] = b4.x; Bs[lk + 1][lr] = b4.y;
        Bs[lk + 2][lr] = b4.z; Bs[lk + 3][lr] = b4.w;
        __syncthreads();
#pragma unroll
        for (int kk = 0; kk < BK; ++kk) {
            float4 av = *(const float4*)&As[kk][ty * 4];
            float4 bv = *(const float4*)&Bs[kk][tx * 4];
            float a[4] = {av.x, av.y, av.z, av.w};
            float b[4] = {bv.x, bv.y, bv.z, bv.w};
#pragma unroll
            for (int i = 0; i < 4; ++i)
#pragma unroll
                for (int j = 0; j < 4; ++j) acc[i][j] += a[i] * b[j];
        }
        __syncthreads();
    }

    const size_t col = n0 + tx * 4;
    float4 bv4 = *(const float4*)(bias + col);
#pragma unroll
    for (int i = 0; i < 4; ++i) {
        const size_t row = m0 + ty * 4 + i;
        float4 o;
        o.x = acc[i][0] + bv4.x; o.y = acc[i][1] + bv4.y;
        o.z = acc[i][2] + bv4.z; o.w = acc[i][3] + bv4.w;
        *(float4*)(Y + row * N + col) = o;
    }
}

// ---------------------------------------------------------------------------
// K2: corr[bh,d] = (1/64) * sum_s sum_c Q[b,(s+d)%L,h,c] * K[b,s,h,c]
// block: 256 threads = 16 lags x 16 channel-groups(float4). Lanes within a
// 16-lane group share d and span c -> 256B coalesced row reads.
// ---------------------------------------------------------------------------
__global__ __launch_bounds__(256)
void corr_kernel(const float* __restrict__ Q, const float* __restrict__ Kt,
                 float* __restrict__ corr) {
    const int tid = threadIdx.x;
    const int cg = tid & 15;                 // channel group (x4 floats)
    const int dl = tid >> 4;                 // 0..15
    const int d  = blockIdx.x * 16 + dl;     // lag
    const int bh = blockIdx.y;
    const int b  = bh >> 4;
    const int h  = bh & 15;
    const size_t base = (size_t)b * L_SZ * D_SZ + h * DK_SZ + cg * 4;

    float4 acc = {0.f, 0.f, 0.f, 0.f};
    for (int s = 0; s < L_SZ; ++s) {
        const int t = (s + d) & (L_SZ - 1);
        float4 q4 = *(const float4*)(Q  + base + (size_t)t * D_SZ);
        float4 k4 = *(const float4*)(Kt + base + (size_t)s * D_SZ);
        acc.x += q4.x * k4.x; acc.y += q4.y * k4.y;
        acc.z += q4.z * k4.z; acc.w += q4.w * k4.w;
    }
    float v = acc.x + acc.y + acc.z + acc.w;
#pragma unroll
    for (int m = 1; m < 16; m <<= 1) v += __shfl_xor(v, m, 64);
    if (cg == 0) corr[(size_t)bh * L_SZ + d] = v * (1.0f / 64.0f);
}

// ---------------------------------------------------------------------------
// K3: per-(b,h) top-7 over 2048 lags (tie -> lowest index, matches lax.top_k)
// then softmax over the 7 values. One block per bh.
// ---------------------------------------------------------------------------
__global__ __launch_bounds__(256)
void topk_softmax(const float* __restrict__ corr, float* __restrict__ w,
                  int* __restrict__ delays) {
    __shared__ float cv[L_SZ];
    __shared__ float rv[256];
    __shared__ int   ri[256];
    __shared__ float topv[TOPK];
    __shared__ int   topi[TOPK];
    const int bh = blockIdx.x, tid = threadIdx.x;

    for (int i = tid; i < L_SZ; i += 256) cv[i] = corr[(size_t)bh * L_SZ + i];
    __syncthreads();

    for (int it = 0; it < TOPK; ++it) {
        float best = -INFINITY; int bi = 0;
        for (int i = tid; i < L_SZ; i += 256) {
            float x = cv[i];
            if (x > best) { best = x; bi = i; }   // strict > keeps lowest idx
        }
        rv[tid] = best; ri[tid] = bi;
        __syncthreads();
        for (int stride = 128; stride > 0; stride >>= 1) {
            if (tid < stride) {
                float ov = rv[tid + stride]; int oi = ri[tid + stride];
                if (ov > rv[tid] || (ov == rv[tid] && oi < ri[tid])) {
                    rv[tid] = ov; ri[tid] = oi;
                }
            }
            __syncthreads();
        }
        if (tid == 0) {
            topv[it] = rv[0]; topi[it] = ri[0];
            cv[ri[0]] = -INFINITY;
        }
        __syncthreads();
    }

    if (tid == 0) {
        float mx = topv[0];       // top_k returns descending -> topv[0] is max
        float e[TOPK], s = 0.f;
#pragma unroll
        for (int i = 0; i < TOPK; ++i) { e[i] = expf(topv[i] - mx); s += e[i]; }
        const float inv = 1.0f / s;
#pragma unroll
        for (int i = 0; i < TOPK; ++i) {
            w[bh * TOPK + i] = e[i] * inv;
            delays[bh * TOPK + i] = topi[i];
        }
    }
}

// ---------------------------------------------------------------------------
// K4: mid[b,t,c] = sum_i w[bh,i] * V[b,(t - delay_i) % L, c]   (c = h*64+cc)
// one thread per float4 of output.
// ---------------------------------------------------------------------------
__global__ __launch_bounds__(256)
void gather_combine(const float* __restrict__ V, const float* __restrict__ w,
                    const int* __restrict__ delays, float* __restrict__ mid) {
    const size_t g = (size_t)blockIdx.x * 256 + threadIdx.x; // B*L*256 threads
    const int c4 = (int)(g & 255);          // float4 index within D
    const int t  = (int)((g >> 8) & (L_SZ - 1));
    const int b  = (int)(g >> 19);
    const int h  = c4 >> 4;
    const int bh = b * H_SZ + h;
    const size_t colbase = (size_t)b * L_SZ * D_SZ + (size_t)c4 * 4;

    float4 acc = {0.f, 0.f, 0.f, 0.f};
#pragma unroll
    for (int i = 0; i < TOPK; ++i) {
        const float wi = w[bh * TOPK + i];
        const int   di = delays[bh * TOPK + i];
        const int   ts = (t - di) & (L_SZ - 1);
        float4 v4 = *(const float4*)(V + colbase + (size_t)ts * D_SZ);
        acc.x += wi * v4.x; acc.y += wi * v4.y;
        acc.z += wi * v4.z; acc.w += wi * v4.w;
    }
    *(float4*)(mid + (size_t)b * L_SZ * D_SZ + (size_t)t * D_SZ + c4 * 4) = acc;
}

// ---------------------------------------------------------------------------
extern "C" void kernel_launch(void* const* d_in, const int* in_sizes, int n_in,
                              void* d_out, int out_size, void* d_ws, size_t ws_size,
                              hipStream_t stream) {
    const float* queries = (const float*)d_in[0];
    const float* keys    = (const float*)d_in[1];
    const float* values  = (const float*)d_in[2];
    const float* Wq = (const float*)d_in[3];
    const float* bq = (const float*)d_in[4];
    const float* Wk = (const float*)d_in[5];
    const float* bk = (const float*)d_in[6];
    const float* Wv = (const float*)d_in[7];
    const float* bv = (const float*)d_in[8];
    const float* Wo = (const float*)d_in[9];
    const float* bo = (const float*)d_in[10];

    const size_t NE = (size_t)M_SZ * D_SZ;   // 16,777,216 floats per tensor
    float* Qb   = (float*)d_ws;
    float* Kb   = Qb + NE;
    float* Vb   = Kb + NE;
    float* corr = Vb + NE;                        // B*H*L = 262144 floats
    float* wbuf = corr + (size_t)B_SZ * H_SZ * L_SZ;  // 896 floats
    int*   dbuf = (int*)(wbuf + B_SZ * H_SZ * TOPK);  // 896 ints
    float* mid  = Qb;   // Q is dead after corr_kernel; reuse its space

    dim3 ggemm(D_SZ / BN, M_SZ / BM);   // (16, 256)

    sgemm_bias_xt<<<ggemm, 256, 0, stream>>>(queries, Wq, bq, Qb, M_SZ, D_SZ, D_SZ);
    sgemm_bias_xt<<<ggemm, 256, 0, stream>>>(keys,    Wk, bk, Kb, M_SZ, D_SZ, D_SZ);
    sgemm_bias_xt<<<ggemm, 256, 0, stream>>>(values,  Wv, bv, Vb, M_SZ, D_SZ, D_SZ);

    corr_kernel<<<dim3(L_SZ / 16, B_SZ * H_SZ), 256, 0, stream>>>(Qb, Kb, corr);

    topk_softmax<<<B_SZ * H_SZ, 256, 0, stream>>>(corr, wbuf, dbuf);

    gather_combine<<<(B_SZ * L_SZ * 256) / 256, 256, 0, stream>>>(Vb, wbuf, dbuf, mid);

    sgemm_bias_xt<<<ggemm, 256, 0, stream>>>(mid, Wo, bo, (float*)d_out, M_SZ, D_SZ, D_SZ);
}

// Round 2
// 2666.791 us; speedup vs baseline: 3.4732x; 3.4732x over previous
//
#include <hip/hip_runtime.h>
#include <hip/hip_bf16.h>
#include <math.h>

#define B_SZ 8
#define L_SZ 2048
#define D_SZ 1024
#define H_SZ 16
#define DK_SZ 64
#define TOPK 7
#define M_SZ (B_SZ * L_SZ)   // 16384

typedef __attribute__((ext_vector_type(8))) short short8;
typedef __attribute__((ext_vector_type(4))) float float4v;
typedef unsigned short ushort_t;
typedef unsigned int uint_t;

__device__ __forceinline__ ushort_t f2bf(float x) {
    uint_t u = __float_as_uint(x);
    uint_t r = (u + 0x7fffu + ((u >> 16) & 1u)) >> 16;   // RNE
    return (ushort_t)r;
}

// ---------------------------------------------------------------------------
// K0: zero the corr accumulator (re-poisoned to 0xAA before every call)
// ---------------------------------------------------------------------------
__global__ __launch_bounds__(256)
void zero_f32(float* __restrict__ p, int n4) {
    int i = blockIdx.x * 256 + threadIdx.x;
    if (i < n4) ((float4*)p)[i] = make_float4(0.f, 0.f, 0.f, 0.f);
}

// ---------------------------------------------------------------------------
// K1: Y = X @ W^T + bias (X:[M,K], W:[N,K] row-major), fp32 compute.
// BF16OUT: store bf16 (for Q,K feeding the MFMA corr) else fp32.
// ---------------------------------------------------------------------------
#define BM 64
#define BN 64
#define BK 16
#define LDP (BM + 4)

template <bool BF16OUT>
__global__ __launch_bounds__(256)
void sgemm_bias_xt(const float* __restrict__ X, const float* __restrict__ W,
                   const float* __restrict__ bias, void* __restrict__ Yv,
                   int M, int N, int K) {
    __shared__ __align__(16) float As[BK][LDP];
    __shared__ __align__(16) float Bs[BK][LDP];
    const int tid = threadIdx.x;
    const int tx = tid & 15;
    const int ty = tid >> 4;
    const size_t m0 = (size_t)blockIdx.y * BM;
    const size_t n0 = (size_t)blockIdx.x * BN;

    const int lr = tid >> 2;
    const int lk = (tid & 3) * 4;

    float acc[4][4];
#pragma unroll
    for (int i = 0; i < 4; ++i)
#pragma unroll
        for (int j = 0; j < 4; ++j) acc[i][j] = 0.f;

    for (int k0 = 0; k0 < K; k0 += BK) {
        float4 a4 = *(const float4*)(X + (m0 + lr) * K + k0 + lk);
        float4 b4 = *(const float4*)(W + (n0 + lr) * K + k0 + lk);
        As[lk + 0][lr] = a4.x; As[lk + 1][lr] = a4.y;
        As[lk + 2][lr] = a4.z; As[lk + 3][lr] = a4.w;
        Bs[lk + 0][lr] = b4.x; Bs[lk + 1][lr] = b4.y;
        Bs[lk + 2][lr] = b4.z; Bs[lk + 3][lr] = b4.w;
        __syncthreads();
#pragma unroll
        for (int kk = 0; kk < BK; ++kk) {
            float4 av = *(const float4*)&As[kk][ty * 4];
            float4 bv = *(const float4*)&Bs[kk][tx * 4];
            float a[4] = {av.x, av.y, av.z, av.w};
            float b[4] = {bv.x, bv.y, bv.z, bv.w};
#pragma unroll
            for (int i = 0; i < 4; ++i)
#pragma unroll
                for (int j = 0; j < 4; ++j) acc[i][j] += a[i] * b[j];
        }
        __syncthreads();
    }

    const size_t col = n0 + tx * 4;
    float4 bv4 = *(const float4*)(bias + col);
#pragma unroll
    for (int i = 0; i < 4; ++i) {
        const size_t row = m0 + ty * 4 + i;
        float o0 = acc[i][0] + bv4.x, o1 = acc[i][1] + bv4.y;
        float o2 = acc[i][2] + bv4.z, o3 = acc[i][3] + bv4.w;
        if (BF16OUT) {
            ushort4 u; u.x = f2bf(o0); u.y = f2bf(o1); u.z = f2bf(o2); u.w = f2bf(o3);
            *(ushort4*)((ushort_t*)Yv + row * N + col) = u;
        } else {
            *(float4*)((float*)Yv + row * N + col) = make_float4(o0, o1, o2, o3);
        }
    }
}

// ---------------------------------------------------------------------------
// K2: corr via tiled-Gram MFMA.
//   corr[bh, d] += (1/64) * G[t, s]  where d = (t - s) mod L, G = Qh·Khᵀ.
// Tile offset j: t-tile = (s-tile + j) mod 128. For fixed j, accumulate over
// all 128 s-tiles in AGPRs (2 MFMA per s-tile, K=64 split 32+32), then ONE
// scatter of the 16x16 tile into corr[(16j + m - n) & 2047] via atomicAdd.
// grid (128 bh, 4 j-quarters) x 256 thr; wave w owns j = jq*32 + w*8 + [0,8).
// No LDS, no barriers: B-frags (K) register-cached across the wave's 8 j's.
// ---------------------------------------------------------------------------
__global__ __launch_bounds__(256)
void corr_mfma(const ushort_t* __restrict__ Qb, const ushort_t* __restrict__ Kb,
               float* __restrict__ corr) {
    const int wave = threadIdx.x >> 6;
    const int lane = threadIdx.x & 63;
    const int bh = blockIdx.x;
    const int jq = blockIdx.y;
    const int b = bh >> 4, h = bh & 15;
    const int jbase = jq * 32 + wave * 8;
    const int lrow = lane & 15;          // m (A) / n (B) index within tile
    const int kgrp = (lane >> 4) * 8;    // k-offset within a 32-wide chunk

    const size_t slice = (size_t)b * L_SZ * D_SZ + (size_t)h * DK_SZ;
    const ushort_t* Qp = Qb + slice + kgrp;
    const ushort_t* Kp = Kb + slice + kgrp;

    float4v acc[8];
#pragma unroll
    for (int i = 0; i < 8; ++i) acc[i] = (float4v){0.f, 0.f, 0.f, 0.f};

    for (int s0 = 0; s0 < 128; ++s0) {
        const size_t srow = (size_t)(s0 * 16 + lrow) * D_SZ;
        short8 bf0 = *(const short8*)(Kp + srow);
        short8 bf1 = *(const short8*)(Kp + srow + 32);
#pragma unroll
        for (int jj = 0; jj < 8; ++jj) {
            const int trow = (((s0 + jbase + jj) & 127) << 4) + lrow;
            const size_t tq = (size_t)trow * D_SZ;
            short8 af0 = *(const short8*)(Qp + tq);
            short8 af1 = *(const short8*)(Qp + tq + 32);
            acc[jj] = __builtin_amdgcn_mfma_f32_16x16x32_bf16(af0, bf0, acc[jj], 0, 0, 0);
            acc[jj] = __builtin_amdgcn_mfma_f32_16x16x32_bf16(af1, bf1, acc[jj], 0, 0, 0);
        }
    }

    // C/D layout (m89-verified): n = lane&15, m = (lane>>4)*4 + reg
    const int n = lane & 15;
    const int mb = (lane >> 4) * 4;
    float* cb = corr + (size_t)bh * L_SZ;
#pragma unroll
    for (int jj = 0; jj < 8; ++jj) {
        const int j16 = (jbase + jj) << 4;
#pragma unroll
        for (int r = 0; r < 4; ++r) {
            const int d = (j16 + mb + r - n) & (L_SZ - 1);
            atomicAdd(cb + d, acc[jj][r] * (1.0f / 64.0f));
        }
    }
}

// ---------------------------------------------------------------------------
// K3: per-(b,h) top-7 (tie -> lowest index) + softmax. One block per bh.
// ---------------------------------------------------------------------------
__global__ __launch_bounds__(256)
void topk_softmax(const float* __restrict__ corr, float* __restrict__ w,
                  int* __restrict__ delays) {
    __shared__ float cv[L_SZ];
    __shared__ float rv[256];
    __shared__ int   ri[256];
    __shared__ float topv[TOPK];
    __shared__ int   topi[TOPK];
    const int bh = blockIdx.x, tid = threadIdx.x;

    for (int i = tid; i < L_SZ; i += 256) cv[i] = corr[(size_t)bh * L_SZ + i];
    __syncthreads();

    for (int it = 0; it < TOPK; ++it) {
        float best = -INFINITY; int bi = 0;
        for (int i = tid; i < L_SZ; i += 256) {
            float x = cv[i];
            if (x > best) { best = x; bi = i; }
        }
        rv[tid] = best; ri[tid] = bi;
        __syncthreads();
        for (int stride = 128; stride > 0; stride >>= 1) {
            if (tid < stride) {
                float ov = rv[tid + stride]; int oi = ri[tid + stride];
                if (ov > rv[tid] || (ov == rv[tid] && oi < ri[tid])) {
                    rv[tid] = ov; ri[tid] = oi;
                }
            }
            __syncthreads();
        }
        if (tid == 0) {
            topv[it] = rv[0]; topi[it] = ri[0];
            cv[ri[0]] = -INFINITY;
        }
        __syncthreads();
    }

    if (tid == 0) {
        float mx = topv[0];
        float e[TOPK], s = 0.f;
#pragma unroll
        for (int i = 0; i < TOPK; ++i) { e[i] = expf(topv[i] - mx); s += e[i]; }
        const float inv = 1.0f / s;
#pragma unroll
        for (int i = 0; i < TOPK; ++i) {
            w[bh * TOPK + i] = e[i] * inv;
            delays[bh * TOPK + i] = topi[i];
        }
    }
}

// ---------------------------------------------------------------------------
// K4: mid[b,t,c] = sum_i w[bh,i] * V[b,(t - delay_i) % L, c]
// ---------------------------------------------------------------------------
__global__ __launch_bounds__(256)
void gather_combine(const float* __restrict__ V, const float* __restrict__ w,
                    const int* __restrict__ delays, float* __restrict__ mid) {
    const size_t g = (size_t)blockIdx.x * 256 + threadIdx.x;
    const int c4 = (int)(g & 255);
    const int t  = (int)((g >> 8) & (L_SZ - 1));
    const int b  = (int)(g >> 19);
    const int h  = c4 >> 4;
    const int bh = b * H_SZ + h;
    const size_t colbase = (size_t)b * L_SZ * D_SZ + (size_t)c4 * 4;

    float4 acc = {0.f, 0.f, 0.f, 0.f};
#pragma unroll
    for (int i = 0; i < TOPK; ++i) {
        const float wi = w[bh * TOPK + i];
        const int   di = delays[bh * TOPK + i];
        const int   ts = (t - di) & (L_SZ - 1);
        float4 v4 = *(const float4*)(V + colbase + (size_t)ts * D_SZ);
        acc.x += wi * v4.x; acc.y += wi * v4.y;
        acc.z += wi * v4.z; acc.w += wi * v4.w;
    }
    *(float4*)(mid + (size_t)b * L_SZ * D_SZ + (size_t)t * D_SZ + c4 * 4) = acc;
}

// ---------------------------------------------------------------------------
extern "C" void kernel_launch(void* const* d_in, const int* in_sizes, int n_in,
                              void* d_out, int out_size, void* d_ws, size_t ws_size,
                              hipStream_t stream) {
    const float* queries = (const float*)d_in[0];
    const float* keys    = (const float*)d_in[1];
    const float* values  = (const float*)d_in[2];
    const float* Wq = (const float*)d_in[3];
    const float* bq = (const float*)d_in[4];
    const float* Wk = (const float*)d_in[5];
    const float* bk = (const float*)d_in[6];
    const float* Wv = (const float*)d_in[7];
    const float* bv = (const float*)d_in[8];
    const float* Wo = (const float*)d_in[9];
    const float* bo = (const float*)d_in[10];

    const size_t NE = (size_t)M_SZ * D_SZ;          // 16.78M elements
    ushort_t* Qb16 = (ushort_t*)d_ws;               // 33.5 MB
    ushort_t* Kb16 = Qb16 + NE;                     // 33.5 MB
    float* Vb   = (float*)(Kb16 + NE);              // 64 MB
    float* corr = Vb + NE;                          // 1 MB (B*H*L fp32)
    float* wbuf = corr + (size_t)B_SZ * H_SZ * L_SZ;
    int*   dbuf = (int*)(wbuf + B_SZ * H_SZ * TOPK);
    float* mid  = (float*)d_ws;  // aliases Qb16+Kb16 (67MB >= 64MB, dead after corr)

    dim3 ggemm(D_SZ / BN, M_SZ / BM);   // (16, 256)

    zero_f32<<<(B_SZ * H_SZ * L_SZ / 4 + 255) / 256, 256, 0, stream>>>(
        corr, B_SZ * H_SZ * L_SZ / 4);

    sgemm_bias_xt<true><<<ggemm, 256, 0, stream>>>(queries, Wq, bq, Qb16, M_SZ, D_SZ, D_SZ);
    sgemm_bias_xt<true><<<ggemm, 256, 0, stream>>>(keys,    Wk, bk, Kb16, M_SZ, D_SZ, D_SZ);
    sgemm_bias_xt<false><<<ggemm, 256, 0, stream>>>(values, Wv, bv, Vb,  M_SZ, D_SZ, D_SZ);

    corr_mfma<<<dim3(B_SZ * H_SZ, 4), 256, 0, stream>>>(Qb16, Kb16, corr);

    topk_softmax<<<B_SZ * H_SZ, 256, 0, stream>>>(corr, wbuf, dbuf);

    gather_combine<<<(M_SZ * 256) / 256, 256, 0, stream>>>(Vb, wbuf, dbuf, mid);

    sgemm_bias_xt<false><<<ggemm, 256, 0, stream>>>(mid, Wo, bo, (float*)d_out, M_SZ, D_SZ, D_SZ);
}